// Round 6
// baseline (113.537 us; speedup 1.0000x reference)
//
#include <hip/hip_runtime.h>
#include <math.h>

#define Bd   4
#define Td   4
#define Cd   32
#define Nd   16384
#define Fd   64
#define Kd   9
#define PADd 4
#define NT   128
#define NROWS (NT + 2*PADd)   // 136
#define NCHUNK (NROWS/4)      // 34 float4 chunks per channel row
#define XP    40              // ushorts per transposed row: 32 c + 8 pad; 80 B pitch (16B-aligned)
#define EPIT  36              // epilogue pitch (dwords)

typedef __attribute__((ext_vector_type(8))) _Float16 half8;   // MFMA A/B frag (4 VGPRs)
typedef __attribute__((ext_vector_type(4))) float    float4v; // MFMA acc frag

#define A_WS_BYTES ((size_t)Td * Kd * 4 * 64 * 8 * 2)  // 147456

// LDS layout (bytes):
//   staging: xt [0,10880) | wlp [10880,15488) | cs [15488,17120)
//   epilogue: epi [0,18432) per-wave 4608 B (reused after barrier)
#define SM_XT  0
#define SM_WL  10880
#define SM_CS  15488
#define SM_BYTES 18432

union FragU { uint4 u; half8 h; };

__device__ __forceinline__ float sigma_as_float(const void* p) {
    int iv = *(const int*)p;
    if (iv > 0 && iv < 1000000) return (float)iv;
    return __int_as_float(iv);
}

__device__ __forceinline__ unsigned short f32_to_f16_bits(float f) {
    _Float16 h = (_Float16)f;           // v_cvt_f16_f32, RNE
    return *reinterpret_cast<unsigned short*>(&h);
}

// ---- prep: weight fp32 [T][F][C][K] -> fp16 A-fragments in ws ----
// idx = (((t*K + k)*4 + ft)*64 + lane)*8 + j ; val = W[t][ft*16+(lane&15)][(lane>>4)*8+j][k]
__global__ void prep_weights(const float* __restrict__ w, unsigned short* __restrict__ a) {
    int idx = blockIdx.x * 256 + threadIdx.x;
    if (idx >= Td * Kd * 4 * 64 * 8) return;
    int j    = idx & 7;
    int lane = (idx >> 3) & 63;
    int ft   = (idx >> 9) & 3;
    int k    = (idx >> 11) % Kd;
    int t    = idx / (Kd * 4 * 64 * 8);
    int m = lane & 15, q = lane >> 4;
    int f = ft * 16 + m;
    int c = q * 8 + j;
    float v = w[(((size_t)t * Fd + f) * Cd + c) * Kd + k];
    a[idx] = f32_to_f16_bits(v);
}

// __launch_bounds__(256, 6): 6 waves/EU -> 6 blocks/CU resident (24 waves/CU).
// VGPR cap ~80; R5 measured 64 VGPR in use, so no spill expected. LDS 6x18432=110KB <= 160KB.
__global__ __launch_bounds__(256, 6)
void swconv_mfma5(const float* __restrict__ x,
                  const float* __restrict__ coords,
                  const unsigned short* __restrict__ aw,
                  const void* __restrict__ sigma_p,
                  float* __restrict__ out)
{
    __shared__ __align__(16) unsigned char smem[SM_BYTES];
    unsigned short (*xt)[XP] = (unsigned short (*)[XP])(smem + SM_XT);   // [NROWS][XP] fp16, transposed
    unsigned int (*wlp)[NT]  = (unsigned int (*)[NT])(smem + SM_WL);    // packed (h,h) per (k, n_local)
    float (*cs)[NROWS]       = (float (*)[NROWS])(smem + SM_CS);

    const int tid  = threadIdx.x;
    const int lane = tid & 63;
    const int wv   = tid >> 6;          // wave 0..3, owns n_local [32*wv, 32*wv+32)
    const int tile = blockIdx.x, t = blockIdx.y, b = blockIdx.z;
    const int n0   = tile * NT;
    const float inv_sigma = 1.0f / sigma_as_float(sigma_p);

    // ---- stage x -> fp16 TRANSPOSED xt[r][c] (float4 global loads) ----
    const float* xbt = x + (size_t)(b * Td + t) * Cd * Nd;
    #pragma unroll 2
    for (int i = tid; i < Cd * NCHUNK; i += 256) {
        int c  = i / NCHUNK;
        int rq = i - c * NCHUNK;
        int nf = n0 - PADd + rq * 4;
        float4 v = make_float4(0.f, 0.f, 0.f, 0.f);
        if (nf >= 0 && nf < Nd)
            v = *reinterpret_cast<const float4*>(xbt + (size_t)c * Nd + nf);
        int r = rq * 4;
        xt[r + 0][c] = f32_to_f16_bits(v.x);
        xt[r + 1][c] = f32_to_f16_bits(v.y);
        xt[r + 2][c] = f32_to_f16_bits(v.z);
        xt[r + 3][c] = f32_to_f16_bits(v.w);
    }

    // ---- stage coords (coalesced) ----
    const float* cbt = coords + (size_t)(b * Td + t) * 3 * Nd;
    for (int i = tid; i < 3 * NROWS; i += 256) {
        int c = i / NROWS, r = i - c * NROWS;
        int n = n0 - PADd + r;
        cs[c][r] = (n >= 0 && n < Nd) ? cbt[(size_t)c * Nd + n] : 0.0f;
    }

    // ---- A-fragment prefetch k=0 (L2-hot, independent of LDS) ----
    const int m = lane & 15, q = lane >> 4;
    const unsigned short* Abase = aw + (size_t)t * Kd * 4 * 64 * 8 + (size_t)lane * 8;
    FragU afr[2][4];
    #pragma unroll
    for (int ft = 0; ft < 4; ++ft)
        afr[0][ft].u = *reinterpret_cast<const uint4*>(Abase + (size_t)ft * 512);

    __syncthreads();

    // ---- distance weights (wave-private: write & read by same wave) ----
    {
        int nl   = wv * 32 + (lane & 31);
        int half = lane >> 5;               // k 0..4 / 5..8
        int il   = nl + PADd;
        float c0 = cs[0][il], c1 = cs[1][il], c2 = cs[2][il];
        int k0 = half ? 5 : 0, k1 = half ? Kd : 5;
        #pragma unroll
        for (int k = k0; k < k1; ++k) {
            float d0 = cs[0][nl + k] - c0;
            float d1 = cs[1][nl + k] - c1;
            float d2 = cs[2][nl + k] - c2;
            float s = d0 * d0 + d1 * d1 + d2 * d2;
            float d = (s > 0.0f) ? sqrtf(s) : 0.0f;
            float w = fmaxf(1.0f - d * inv_sigma, 0.0f);
            wlp[k][nl] = (unsigned int)f32_to_f16_bits(w) * 0x00010001u;  // (h,h)
        }
    }

    float4v acc[4][2];
    #pragma unroll
    for (int ft = 0; ft < 4; ++ft)
        #pragma unroll
        for (int nt = 0; nt < 2; ++nt)
            acc[ft][nt] = (float4v){0.f, 0.f, 0.f, 0.f};

    for (int k = 0; k < Kd; ++k) {
        const int cur = k & 1;
        if (k + 1 < Kd) {
            #pragma unroll
            for (int ft = 0; ft < 4; ++ft)
                afr[cur ^ 1][ft].u = *reinterpret_cast<const uint4*>(Abase + (size_t)((k + 1) * 4 + ft) * 512);
        }
        #pragma unroll
        for (int nt = 0; nt < 2; ++nt) {
            const int ncol = wv * 32 + nt * 16 + m;   // n_local of this lane's column
            const int r    = ncol + k;                // xt row (tap nn = n + k - 4)
            FragU xv; xv.u = *reinterpret_cast<const uint4*>(&xt[r][q * 8]);  // 8 c's, one ds_read_b128
            unsigned int wp = wlp[k][ncol];
            FragU ww; ww.u = make_uint4(wp, wp, wp, wp);
            half8 bfr = xv.h * ww.h;                  // 4x v_pk_mul_f16
            #pragma unroll
            for (int ft = 0; ft < 4; ++ft)
                acc[ft][nt] = __builtin_amdgcn_mfma_f32_16x16x32_f16(afr[cur][ft].h, bfr, acc[ft][nt], 0, 0, 0);
        }
    }

    // ---- epilogue: LDS transpose -> full-line float4 stores ----
    __syncthreads();   // xt/wlp dead for everyone before epi overwrite
    float (*epi)[EPIT] = (float (*)[EPIT])(smem + (size_t)wv * 32 * EPIT * 4);  // per-wave [32][36]

    float* ob = out + (size_t)(b * Td + t) * Fd * Nd + n0 + wv * 32;
    #pragma unroll
    for (int fc = 0; fc < 2; ++fc) {          // f chunks [0,32) / [32,64)
        #pragma unroll
        for (int ft2 = 0; ft2 < 2; ++ft2) {
            const int ft = fc * 2 + ft2;
            #pragma unroll
            for (int nt = 0; nt < 2; ++nt) {
                const int np = nt * 16 + m;
                #pragma unroll
                for (int rr = 0; rr < 4; ++rr)
                    epi[ft2 * 16 + q * 4 + rr][np] = acc[ft][nt][rr];
            }
        }
        #pragma unroll
        for (int inst = 0; inst < 4; ++inst) {
            const int fl = inst * 8 + (lane >> 3);
            const int np = (lane & 7) * 4;
            float4 v = *reinterpret_cast<const float4*>(&epi[fl][np]);
            *reinterpret_cast<float4*>(ob + (size_t)(fc * 32 + fl) * Nd + np) = v;
        }
    }
}

// ---- fallback fp32 kernel (ws too small) ----
__global__ __launch_bounds__(256, 4)
void swconv_f32_kernel(const float* __restrict__ x,
                       const float* __restrict__ coords,
                       const float* __restrict__ weight,
                       const void*  __restrict__ sigma_p,
                       float* __restrict__ out)
{
    __shared__ float xsf[Cd][NROWS + 1];
    __shared__ float csf[3][NROWS + 1];
    const int tid = threadIdx.x;
    const int tile = blockIdx.x, t = blockIdx.y, b = blockIdx.z;
    const int n0 = tile * NT;
    const float inv_sigma = 1.0f / sigma_as_float(sigma_p);

    const float* xbt = x + (size_t)(b * Td + t) * Cd * Nd;
    for (int idx = tid; idx < Cd * NROWS; idx += 256) {
        int c = idx / NROWS, i = idx - c * NROWS, n = n0 - PADd + i;
        xsf[c][i] = (n >= 0 && n < Nd) ? xbt[(size_t)c * Nd + n] : 0.0f;
    }
    const float* cbt = coords + (size_t)(b * Td + t) * 3 * Nd;
    for (int idx = tid; idx < 3 * NROWS; idx += 256) {
        int c = idx / NROWS, i = idx - c * NROWS, n = n0 - PADd + i;
        csf[c][i] = (n >= 0 && n < Nd) ? cbt[(size_t)c * Nd + n] : 0.0f;
    }
    __syncthreads();
    if (tid >= NT) return;

    float wk[Kd];
    {
        const float c0 = csf[0][tid + PADd], c1 = csf[1][tid + PADd], c2 = csf[2][tid + PADd];
        #pragma unroll
        for (int k = 0; k < Kd; ++k) {
            float d0 = csf[0][tid + k] - c0, d1 = csf[1][tid + k] - c1, d2 = csf[2][tid + k] - c2;
            float s = d0 * d0 + d1 * d1 + d2 * d2;
            float d = (s > 0.0f) ? sqrtf(s) : 0.0f;
            wk[k] = fmaxf(1.0f - d * inv_sigma, 0.0f);
        }
    }
    float accf[Fd];
    #pragma unroll
    for (int f = 0; f < Fd; ++f) accf[f] = 0.0f;
    const float* wt = weight + (size_t)t * Fd * Cd * Kd;
    for (int c = 0; c < Cd; ++c) {
        float xv[Kd];
        #pragma unroll
        for (int k = 0; k < Kd; ++k) xv[k] = xsf[c][tid + k];
        const float* wp = wt + c * Kd;
        #pragma unroll
        for (int k = 0; k < Kd; ++k) {
            float v = xv[k] * wk[k];
            #pragma unroll
            for (int f = 0; f < Fd; ++f)
                accf[f] = fmaf(v, wp[(size_t)f * Cd * Kd + k], accf[f]);
        }
    }
    float* op = out + (size_t)(b * Td + t) * Fd * Nd + n0 + tid;
    #pragma unroll
    for (int f = 0; f < Fd; ++f) op[(size_t)f * Nd] = accf[f];
}

extern "C" void kernel_launch(void* const* d_in, const int* in_sizes, int n_in,
                              void* d_out, int out_size, void* d_ws, size_t ws_size,
                              hipStream_t stream) {
    const float* x      = (const float*)d_in[0];
    const float* coords = (const float*)d_in[1];
    const float* weight = (const float*)d_in[2];
    const void*  sigma  = d_in[3];
    float* out = (float*)d_out;

    if (ws_size >= A_WS_BYTES) {
        unsigned short* aw = (unsigned short*)d_ws;
        prep_weights<<<(Td * Kd * 4 * 64 * 8 + 255) / 256, 256, 0, stream>>>(weight, aw);
        dim3 grid(Nd / NT, Td, Bd);   // 2048 blocks
        swconv_mfma5<<<grid, dim3(256), 0, stream>>>(x, coords, aw, sigma, out);
    } else {
        dim3 grid(Nd / NT, Td, Bd);
        swconv_f32_kernel<<<grid, dim3(256), 0, stream>>>(x, coords, weight, sigma, out);
    }
}

// Round 7
// 113.155 us; speedup vs baseline: 1.0034x; 1.0034x over previous
//
#include <hip/hip_runtime.h>
#include <math.h>

#define Bd   4
#define Td   4
#define Cd   32
#define Nd   16384
#define Fd   64
#define Kd   9
#define PADd 4
#define NT   128
#define NROWS (NT + 2*PADd)   // 136
#define NCHUNK (NROWS/4)      // 34 float4 chunks per channel row
#define XP    40              // ushorts per transposed row: 32 c + 8 pad
#define EPIT  36              // epilogue pitch (dwords)

typedef __attribute__((ext_vector_type(8))) _Float16 half8;   // MFMA A/B frag
typedef __attribute__((ext_vector_type(4))) float    float4v; // MFMA acc frag

#define A_WS_BYTES ((size_t)Td * Kd * 4 * 64 * 8 * 2)  // 147456

// LDS layout (bytes) — double-buffered pipeline:
//   xt0 [0,10880) | xt1 [10880,21760) | wl0 [21760,26368) | wl1 [26368,30976)
//   cs0 [30976,32608) | cs1 [32608,34240)
//   epi (per-wave 2304 B x 4 = 9216) overlays dead xt0 region at offset 0
#define SM_XT0 0
#define SM_XT1 10880
#define SM_WL0 21760
#define SM_WL1 26368
#define SM_CS0 30976
#define SM_CS1 32608
#define SM_BYTES 34240

union FragU { uint4 u; half8 h; };

__device__ __forceinline__ float sigma_as_float(const void* p) {
    int iv = *(const int*)p;
    if (iv > 0 && iv < 1000000) return (float)iv;
    return __int_as_float(iv);
}

__device__ __forceinline__ unsigned short f32_to_f16_bits(float f) {
    _Float16 h = (_Float16)f;           // v_cvt_f16_f32, RNE
    return *reinterpret_cast<unsigned short*>(&h);
}

// ---- prep: weight fp32 [T][F][C][K] -> fp16 A-fragments in ws ----
__global__ void prep_weights(const float* __restrict__ w, unsigned short* __restrict__ a) {
    int idx = blockIdx.x * 256 + threadIdx.x;
    if (idx >= Td * Kd * 4 * 64 * 8) return;
    int j    = idx & 7;
    int lane = (idx >> 3) & 63;
    int ft   = (idx >> 9) & 3;
    int k    = (idx >> 11) % Kd;
    int t    = idx / (Kd * 4 * 64 * 8);
    int m = lane & 15, q = lane >> 4;
    int f = ft * 16 + m;
    int c = q * 8 + j;
    float v = w[(((size_t)t * Fd + f) * Cd + c) * Kd + k];
    a[idx] = f32_to_f16_bits(v);
}

// ---- staging helpers: issue loads raw (clamped addr), select-to-zero at write ----
__device__ __forceinline__ void issue_x(const float* __restrict__ xbt, int n0, int tid, float4 xv[5]) {
    #pragma unroll
    for (int i = 0; i < 5; ++i) {
        int gi = tid + 256 * i;
        if (i < 4 || tid < Cd * NCHUNK - 1024) {       // 1088 total; last iter tid<64
            int c = gi / NCHUNK, rq = gi - c * NCHUNK;
            int nf = n0 - PADd + rq * 4;
            int nc = min(max(nf, 0), Nd - 4);
            xv[i] = *reinterpret_cast<const float4*>(xbt + (size_t)c * Nd + nc);
        }
    }
}

__device__ __forceinline__ void write_x(unsigned short (*xt)[XP], int n0, int tid, const float4 xv[5]) {
    #pragma unroll
    for (int i = 0; i < 5; ++i) {
        int gi = tid + 256 * i;
        if (i < 4 || tid < Cd * NCHUNK - 1024) {
            int c = gi / NCHUNK, rq = gi - c * NCHUNK;
            int nf = n0 - PADd + rq * 4;
            bool ok = (nf >= 0) && (nf <= Nd - 4);     // chunks fully in or fully out
            float4 v = ok ? xv[i] : make_float4(0.f, 0.f, 0.f, 0.f);
            int r = rq * 4;
            xt[r + 0][c] = f32_to_f16_bits(v.x);
            xt[r + 1][c] = f32_to_f16_bits(v.y);
            xt[r + 2][c] = f32_to_f16_bits(v.z);
            xt[r + 3][c] = f32_to_f16_bits(v.w);
        }
    }
}

__device__ __forceinline__ void issue_c(const float* __restrict__ cbt, int n0, int tid, float cv[2]) {
    #pragma unroll
    for (int i = 0; i < 2; ++i) {
        int gi = tid + 256 * i;
        if (i < 1 || tid < 3 * NROWS - 256) {          // 408 total; last iter tid<152
            int c = gi / NROWS, r = gi - c * NROWS;
            int n = n0 - PADd + r;
            int nc = min(max(n, 0), Nd - 1);
            cv[i] = cbt[(size_t)c * Nd + nc];
        }
    }
}

__device__ __forceinline__ void write_c(float (*cs)[NROWS], int n0, int tid, const float cv[2]) {
    #pragma unroll
    for (int i = 0; i < 2; ++i) {
        int gi = tid + 256 * i;
        if (i < 1 || tid < 3 * NROWS - 256) {
            int c = gi / NROWS, r = gi - c * NROWS;
            int n = n0 - PADd + r;
            bool ok = ((unsigned)n < (unsigned)Nd);
            cs[c][r] = ok ? cv[i] : 0.0f;
        }
    }
}

// ---- distance weights: wave-private (write & read same wave, no barrier) ----
__device__ __forceinline__ void wl_comp(const float (*cs)[NROWS], unsigned int (*wlp)[NT],
                                        int wv, int lane, float inv_sigma) {
    int nl   = wv * 32 + (lane & 31);
    int half = lane >> 5;               // k 0..4 / 5..8
    int il   = nl + PADd;
    float c0 = cs[0][il], c1 = cs[1][il], c2 = cs[2][il];
    int k0 = half ? 5 : 0, k1 = half ? Kd : 5;
    #pragma unroll
    for (int k = k0; k < k1; ++k) {
        float d0 = cs[0][nl + k] - c0;
        float d1 = cs[1][nl + k] - c1;
        float d2 = cs[2][nl + k] - c2;
        float s = d0 * d0 + d1 * d1 + d2 * d2;
        float d = (s > 0.0f) ? sqrtf(s) : 0.0f;
        float w = fmaxf(1.0f - d * inv_sigma, 0.0f);
        wlp[k][nl] = (unsigned int)f32_to_f16_bits(w) * 0x00010001u;  // packed (h,h)
    }
}

// ---- the 9-tap MFMA loop over one staged tile ----
__device__ __forceinline__ void kloop(const unsigned char* xt_, const unsigned char* wl_,
                                      const unsigned short* __restrict__ Abase, const FragU a0[4],
                                      int wv, int m, int q, float4v acc[4][2]) {
    const unsigned short (*xt)[XP] = (const unsigned short (*)[XP])xt_;
    const unsigned int (*wlp)[NT]  = (const unsigned int (*)[NT])wl_;
    FragU afr[2][4];
    #pragma unroll
    for (int ft = 0; ft < 4; ++ft) afr[0][ft] = a0[ft];
    for (int k = 0; k < Kd; ++k) {
        const int cur = k & 1;
        if (k + 1 < Kd) {
            #pragma unroll
            for (int ft = 0; ft < 4; ++ft)
                afr[cur ^ 1][ft].u = *reinterpret_cast<const uint4*>(Abase + (size_t)((k + 1) * 4 + ft) * 512);
        }
        #pragma unroll
        for (int nt = 0; nt < 2; ++nt) {
            const int ncol = wv * 32 + nt * 16 + m;
            const int r    = ncol + k;
            FragU xv; xv.u = *reinterpret_cast<const uint4*>(&xt[r][q * 8]);  // ds_read_b128
            unsigned int wp = wlp[k][ncol];
            FragU ww; ww.u = make_uint4(wp, wp, wp, wp);
            half8 bfr = xv.h * ww.h;                  // 4x v_pk_mul_f16
            #pragma unroll
            for (int ft = 0; ft < 4; ++ft)
                acc[ft][nt] = __builtin_amdgcn_mfma_f32_16x16x32_f16(afr[cur][ft].h, bfr, acc[ft][nt], 0, 0, 0);
        }
    }
}

// ---- epilogue: per-wave 16-f-row LDS transpose passes -> full-line float4 stores ----
__device__ __forceinline__ void epilogue(float* __restrict__ obt, int n0,
                                         int wv, int lane, int m, int q,
                                         unsigned char* smem, const float4v acc[4][2]) {
    float (*epi)[EPIT] = (float (*)[EPIT])(smem + (size_t)wv * 16 * EPIT * 4);  // 2304 B/wave in dead xt0
    float* ob = obt + n0 + wv * 32;
    #pragma unroll
    for (int ft = 0; ft < 4; ++ft) {       // 16 f-rows per pass
        #pragma unroll
        for (int nt = 0; nt < 2; ++nt) {
            const int np = nt * 16 + m;
            #pragma unroll
            for (int rr = 0; rr < 4; ++rr)
                epi[q * 4 + rr][np] = acc[ft][nt][rr];
        }
        #pragma unroll
        for (int inst = 0; inst < 2; ++inst) {
            const int fl = inst * 8 + (lane >> 3);
            const int np = (lane & 7) * 4;
            float4 v = *reinterpret_cast<const float4*>(&epi[fl][np]);
            *reinterpret_cast<float4*>(ob + (size_t)(ft * 16 + fl) * Nd + np) = v;
        }
    }
}

// 2 tiles per block, software-pipelined: tile1 fetch under tile0 compute,
// tile0 stores under tile1 compute. LDS 34240 B -> 4 blocks/CU.
__global__ __launch_bounds__(256, 4)
void swconv_pipe(const float* __restrict__ x,
                 const float* __restrict__ coords,
                 const unsigned short* __restrict__ aw,
                 const void* __restrict__ sigma_p,
                 float* __restrict__ out)
{
    __shared__ __align__(16) unsigned char smem[SM_BYTES];

    const int tid  = threadIdx.x;
    const int lane = tid & 63;
    const int wv   = tid >> 6;
    const int m    = lane & 15, q = lane >> 4;
    const int pair = blockIdx.x, t = blockIdx.y, b = blockIdx.z;
    const int n00  = pair * (2 * NT);
    const int n01  = n00 + NT;
    const float inv_sigma = 1.0f / sigma_as_float(sigma_p);

    const float* xbt = x + (size_t)(b * Td + t) * Cd * Nd;
    const float* cbt = coords + (size_t)(b * Td + t) * 3 * Nd;
    const unsigned short* Abase = aw + (size_t)t * Kd * 4 * 64 * 8 + (size_t)lane * 8;
    float* obt = out + (size_t)(b * Td + t) * Fd * Nd;

    float4 xv[5]; float cv[2];
    FragU a0[4];

    // ---- stage tile 0 ----
    issue_x(xbt, n00, tid, xv);
    issue_c(cbt, n00, tid, cv);
    #pragma unroll
    for (int ft = 0; ft < 4; ++ft)
        a0[ft].u = *reinterpret_cast<const uint4*>(Abase + (size_t)ft * 512);
    write_x((unsigned short (*)[XP])(smem + SM_XT0), n00, tid, xv);
    write_c((float (*)[NROWS])(smem + SM_CS0), n00, tid, cv);
    __syncthreads();
    wl_comp((const float (*)[NROWS])(smem + SM_CS0), (unsigned int (*)[NT])(smem + SM_WL0),
            wv, lane, inv_sigma);

    // ---- issue tile 1 global loads: fly during tile 0 compute ----
    issue_x(xbt, n01, tid, xv);
    issue_c(cbt, n01, tid, cv);

    float4v acc[4][2];
    #pragma unroll
    for (int ft = 0; ft < 4; ++ft)
        #pragma unroll
        for (int nt = 0; nt < 2; ++nt)
            acc[ft][nt] = (float4v){0.f, 0.f, 0.f, 0.f};
    kloop(smem + SM_XT0, smem + SM_WL0, Abase, a0, wv, m, q, acc);

    // reload k=0 A-frags for tile 1 (L2-hot) while staging waits resolve
    #pragma unroll
    for (int ft = 0; ft < 4; ++ft)
        a0[ft].u = *reinterpret_cast<const uint4*>(Abase + (size_t)ft * 512);

    // ---- stage tile 1 (vmcnt wait lands here, after kloop0) ----
    write_x((unsigned short (*)[XP])(smem + SM_XT1), n01, tid, xv);
    write_c((float (*)[NROWS])(smem + SM_CS1), n01, tid, cv);
    __syncthreads();
    wl_comp((const float (*)[NROWS])(smem + SM_CS1), (unsigned int (*)[NT])(smem + SM_WL1),
            wv, lane, inv_sigma);

    // ---- epilogue tile 0 (epi overlays dead xt0; stores fly during kloop1) ----
    epilogue(obt, n00, wv, lane, m, q, smem, acc);

    // ---- compute + store tile 1 ----
    #pragma unroll
    for (int ft = 0; ft < 4; ++ft)
        #pragma unroll
        for (int nt = 0; nt < 2; ++nt)
            acc[ft][nt] = (float4v){0.f, 0.f, 0.f, 0.f};
    kloop(smem + SM_XT1, smem + SM_WL1, Abase, a0, wv, m, q, acc);
    epilogue(obt, n01, wv, lane, m, q, smem, acc);
}

// ---- fallback fp32 kernel (ws too small) ----
__global__ __launch_bounds__(256, 4)
void swconv_f32_kernel(const float* __restrict__ x,
                       const float* __restrict__ coords,
                       const float* __restrict__ weight,
                       const void*  __restrict__ sigma_p,
                       float* __restrict__ out)
{
    __shared__ float xsf[Cd][NROWS + 1];
    __shared__ float csf[3][NROWS + 1];
    const int tid = threadIdx.x;
    const int tile = blockIdx.x, t = blockIdx.y, b = blockIdx.z;
    const int n0 = tile * NT;
    const float inv_sigma = 1.0f / sigma_as_float(sigma_p);

    const float* xbt = x + (size_t)(b * Td + t) * Cd * Nd;
    for (int idx = tid; idx < Cd * NROWS; idx += 256) {
        int c = idx / NROWS, i = idx - c * NROWS, n = n0 - PADd + i;
        xsf[c][i] = (n >= 0 && n < Nd) ? xbt[(size_t)c * Nd + n] : 0.0f;
    }
    const float* cbt = coords + (size_t)(b * Td + t) * 3 * Nd;
    for (int idx = tid; idx < 3 * NROWS; idx += 256) {
        int c = idx / NROWS, i = idx - c * NROWS, n = n0 - PADd + i;
        csf[c][i] = (n >= 0 && n < Nd) ? cbt[(size_t)c * Nd + n] : 0.0f;
    }
    __syncthreads();
    if (tid >= NT) return;

    float wk[Kd];
    {
        const float c0 = csf[0][tid + PADd], c1 = csf[1][tid + PADd], c2 = csf[2][tid + PADd];
        #pragma unroll
        for (int k = 0; k < Kd; ++k) {
            float d0 = csf[0][tid + k] - c0, d1 = csf[1][tid + k] - c1, d2 = csf[2][tid + k] - c2;
            float s = d0 * d0 + d1 * d1 + d2 * d2;
            float d = (s > 0.0f) ? sqrtf(s) : 0.0f;
            wk[k] = fmaxf(1.0f - d * inv_sigma, 0.0f);
        }
    }
    float accf[Fd];
    #pragma unroll
    for (int f = 0; f < Fd; ++f) accf[f] = 0.0f;
    const float* wt = weight + (size_t)t * Fd * Cd * Kd;
    for (int c = 0; c < Cd; ++c) {
        float xvv[Kd];
        #pragma unroll
        for (int k = 0; k < Kd; ++k) xvv[k] = xsf[c][tid + k];
        const float* wp = wt + c * Kd;
        #pragma unroll
        for (int k = 0; k < Kd; ++k) {
            float v = xvv[k] * wk[k];
            #pragma unroll
            for (int f = 0; f < Fd; ++f)
                accf[f] = fmaf(v, wp[(size_t)f * Cd * Kd + k], accf[f]);
        }
    }
    float* op = out + (size_t)(b * Td + t) * Fd * Nd + n0 + tid;
    #pragma unroll
    for (int f = 0; f < Fd; ++f) op[(size_t)f * Nd] = accf[f];
}

extern "C" void kernel_launch(void* const* d_in, const int* in_sizes, int n_in,
                              void* d_out, int out_size, void* d_ws, size_t ws_size,
                              hipStream_t stream) {
    const float* x      = (const float*)d_in[0];
    const float* coords = (const float*)d_in[1];
    const float* weight = (const float*)d_in[2];
    const void*  sigma  = d_in[3];
    float* out = (float*)d_out;

    if (ws_size >= A_WS_BYTES) {
        unsigned short* aw = (unsigned short*)d_ws;
        prep_weights<<<(Td * Kd * 4 * 64 * 8 + 255) / 256, 256, 0, stream>>>(weight, aw);
        dim3 grid(Nd / (2 * NT), Td, Bd);   // 64 x 4 x 4 = 1024 blocks, 2 tiles each
        swconv_pipe<<<grid, dim3(256), 0, stream>>>(x, coords, aw, sigma, out);
    } else {
        dim3 grid(Nd / NT, Td, Bd);
        swconv_f32_kernel<<<grid, dim3(256), 0, stream>>>(x, coords, weight, sigma, out);
    }
}